// Round 1
// baseline (395.249 us; speedup 1.0000x reference)
//
#include <hip/hip_runtime.h>
#include <hip/hip_bf16.h>

#define IN_F 1024
#define OUT_F 1024
#define KTOT (IN_F * 9)   // 9216: channel-major, k = c*1024 + i, c=0 is silu
#define M_ROWS 8192

typedef short bf16x8 __attribute__((ext_vector_type(8)));
typedef float f32x4 __attribute__((ext_vector_type(4)));

#define AS1 __attribute__((address_space(1)))
#define AS3 __attribute__((address_space(3)))

// ---------------------------------------------------------------- basis eval
__device__ __forceinline__ void kan_basis(float xv, const float* __restrict__ g,
                                          float* __restrict__ b, float& silu) {
  float t[11];
#pragma unroll
  for (int j = 0; j < 11; ++j)
    t[j] = (xv >= g[j] && xv < g[j + 1]) ? 1.0f : 0.0f;
#pragma unroll
  for (int k = 1; k <= 3; ++k) {
#pragma unroll
    for (int j = 0; j < 11 - k; ++j) {
      float left  = (xv - g[j]) / (g[j + k] - g[j]);
      float right = (g[j + k + 1] - xv) / (g[j + k + 1] - g[j + 1]);
      t[j] = left * t[j] + right * t[j + 1];
    }
  }
#pragma unroll
  for (int j = 0; j < 8; ++j) b[j] = t[j];
  silu = xv / (1.0f + expf(-xv));
}

// ------------------------------------------------- A expansion (fp32 -> bf16)
// A[n][k] with k = c*1024 + i  (c=0: silu(x), c=1..8: spline bases)
__global__ __launch_bounds__(256) void expand_a(
    const float* __restrict__ x, const float* __restrict__ grid,
    __hip_bfloat16* __restrict__ A, int row0, int nrows) {
  int idx = blockIdx.x * 256 + threadIdx.x;
  if (idx >= nrows * IN_F) return;
  int n = idx >> 10;
  int i = idx & (IN_F - 1);
  float xv = x[(size_t)(row0 + n) * IN_F + i];
  float g[12];
  const float* gp = grid + i * 12;
#pragma unroll
  for (int t = 0; t < 12; ++t) g[t] = gp[t];
  float b[8], s;
  kan_basis(xv, g, b, s);
  size_t base = (size_t)n * KTOT + i;
  A[base] = __float2bfloat16(s);
#pragma unroll
  for (int c = 0; c < 8; ++c)
    A[base + (size_t)(c + 1) * IN_F] = __float2bfloat16(b[c]);
}

// --------------------------------------------------- B packing (fp32 -> bf16)
// B[o][k] with k = c*1024 + i (c=0: base_weight, c>0: spline_weight*scaler)
__global__ __launch_bounds__(256) void pack_b(
    const float* __restrict__ bw, const float* __restrict__ sw,
    const float* __restrict__ sc, __hip_bfloat16* __restrict__ B) {
  int idx = blockIdx.x * 256 + threadIdx.x;
  if (idx >= OUT_F * IN_F) return;
  float scl = sc[idx];
  size_t base = (size_t)(idx >> 10) * KTOT + (idx & (IN_F - 1));
  B[base] = __float2bfloat16(bw[idx]);
  const float* swp = sw + (size_t)idx * 8;
#pragma unroll
  for (int c = 0; c < 8; ++c)
    B[base + (size_t)(c + 1) * IN_F] = __float2bfloat16(swp[c] * scl);
}

// -------------------------------------------------------------- bf16 GEMM BT
// C(M x 1024) = A(M x K) * B(1024 x K)^T ; m97-structure: 128x128 tile, BK=64
#define BM 128
#define BN 128
#define BK 64

__device__ __forceinline__ void gld16(const __hip_bfloat16* g, __hip_bfloat16* l) {
  __builtin_amdgcn_global_load_lds((AS1 void*)g, (AS3 void*)l, 16, 0, 0);
}

__global__ __launch_bounds__(256, 2) void gemm_bt(
    const __hip_bfloat16* __restrict__ A, const __hip_bfloat16* __restrict__ B,
    float* __restrict__ C, int M, int K) {
  __shared__ __align__(16) __hip_bfloat16 As[BM * BK];
  __shared__ __align__(16) __hip_bfloat16 Bs[BN * BK];

  const int bn = blockIdx.x & 7;   // 1024/128 = 8 column blocks
  const int bm = blockIdx.x >> 3;
  const int tid = threadIdx.x;
  const int lane = tid & 63;
  const int wv = tid >> 6;
  const int wm = wv >> 1, wn = wv & 1;
  const int l15 = lane & 15, lhi = lane >> 4;

  f32x4 acc[4][4];
#pragma unroll
  for (int m = 0; m < 4; ++m)
#pragma unroll
    for (int n = 0; n < 4; ++n) acc[m][n] = f32x4{0.f, 0.f, 0.f, 0.f};

  // staging geometry: tile = 1024 16B-chunks; wave op covers 64 chunks (1 KiB)
  int arow[4], ac8[4];
#pragma unroll
  for (int j = 0; j < 4; ++j) {
    int chunk = (wv * 4 + j) * 64 + lane;
    arow[j] = chunk >> 3;   // row in [0,128)
    ac8[j] = chunk & 7;     // 16B-chunk within the 64-wide row
  }

  for (int k0 = 0; k0 < K; k0 += BK) {
#pragma unroll
    for (int j = 0; j < 4; ++j) {
      int op = wv * 4 + j;
      gld16(A + (size_t)(bm * BM + arow[j]) * K + k0 + ac8[j] * 8, As + op * 512);
      gld16(B + (size_t)(bn * BN + arow[j]) * K + k0 + ac8[j] * 8, Bs + op * 512);
    }
    __syncthreads();  // compiler drains vmcnt(0) before s_barrier
#pragma unroll
    for (int kk = 0; kk < 2; ++kk) {
      bf16x8 af[4], bfr[4];
#pragma unroll
      for (int m = 0; m < 4; ++m)
        af[m] = *(const bf16x8*)(&As[(wm * 64 + m * 16 + l15) * BK + kk * 32 + lhi * 8]);
#pragma unroll
      for (int n = 0; n < 4; ++n)
        bfr[n] = *(const bf16x8*)(&Bs[(wn * 64 + n * 16 + l15) * BK + kk * 32 + lhi * 8]);
#pragma unroll
      for (int m = 0; m < 4; ++m)
#pragma unroll
        for (int n = 0; n < 4; ++n)
          acc[m][n] = __builtin_amdgcn_mfma_f32_16x16x32_bf16(af[m], bfr[n], acc[m][n], 0, 0, 0);
    }
    __syncthreads();
  }

  // epilogue: C/D mapping col = lane&15, row = (lane>>4)*4 + reg  [m89-verified]
#pragma unroll
  for (int m = 0; m < 4; ++m)
#pragma unroll
    for (int n = 0; n < 4; ++n) {
      int col = bn * BN + wn * 64 + n * 16 + l15;
      int row0 = bm * BM + wm * 64 + m * 16 + lhi * 4;
#pragma unroll
      for (int j = 0; j < 4; ++j)
        C[(size_t)(row0 + j) * OUT_F + col] = acc[m][n][j];
    }
}

// ------------------------------------------------ naive fallback (insurance)
__global__ __launch_bounds__(256) void kan_naive(
    const float* __restrict__ x, const float* __restrict__ grid,
    const float* __restrict__ bw, const float* __restrict__ sw,
    const float* __restrict__ sc, float* __restrict__ out) {
  __shared__ float s_act[IN_F];
  __shared__ float s_bas[IN_F * 8];
  int n = blockIdx.x;
  for (int i = threadIdx.x; i < IN_F; i += 256) {
    float xv = x[(size_t)n * IN_F + i];
    float g[12];
    const float* gp = grid + i * 12;
#pragma unroll
    for (int t = 0; t < 12; ++t) g[t] = gp[t];
    float b[8], s;
    kan_basis(xv, g, b, s);
    s_act[i] = s;
#pragma unroll
    for (int c = 0; c < 8; ++c) s_bas[i * 8 + c] = b[c];
  }
  __syncthreads();
  for (int o = threadIdx.x; o < OUT_F; o += 256) {
    float acc = 0.f;
    const float* bwo = bw + (size_t)o * IN_F;
    const float* swo = sw + (size_t)o * IN_F * 8;
    const float* sco = sc + (size_t)o * IN_F;
    for (int i = 0; i < IN_F; ++i) {
      acc += s_act[i] * bwo[i];
      float p = 0.f;
#pragma unroll
      for (int c = 0; c < 8; ++c) p += s_bas[i * 8 + c] * swo[i * 8 + c];
      acc += p * sco[i];
    }
    out[(size_t)n * OUT_F + o] = acc;
  }
}

// ---------------------------------------------------------------- launch
extern "C" void kernel_launch(void* const* d_in, const int* in_sizes, int n_in,
                              void* d_out, int out_size, void* d_ws, size_t ws_size,
                              hipStream_t stream) {
  const float* x  = (const float*)d_in[0];
  const float* grid = (const float*)d_in[1];
  const float* bw = (const float*)d_in[2];
  const float* sw = (const float*)d_in[3];
  const float* sc = (const float*)d_in[4];
  float* out = (float*)d_out;

  const size_t Bbytes = (size_t)OUT_F * KTOT * 2;            // 18.9 MB
  const size_t rowBytes = (size_t)KTOT * 2;                  // 18 KB / A-row

  if (ws_size >= Bbytes + 128 * rowBytes) {
    __hip_bfloat16* Bp = (__hip_bfloat16*)d_ws;
    __hip_bfloat16* Ap = (__hip_bfloat16*)((char*)d_ws + Bbytes);
    size_t arows = (ws_size - Bbytes) / rowBytes;
    int chunk = (int)((arows / 128) * 128);
    if (chunk > M_ROWS) chunk = M_ROWS;

    pack_b<<<(OUT_F * IN_F + 255) / 256, 256, 0, stream>>>(bw, sw, sc, Bp);
    for (int r0 = 0; r0 < M_ROWS; r0 += chunk) {
      int rows = M_ROWS - r0 < chunk ? M_ROWS - r0 : chunk;   // multiple of 128
      expand_a<<<(rows * IN_F + 255) / 256, 256, 0, stream>>>(x, grid, Ap, r0, rows);
      gemm_bt<<<(rows / BM) * 8, 256, 0, stream>>>(Ap, Bp, out + (size_t)r0 * OUT_F,
                                                   rows, KTOT);
    }
  } else {
    kan_naive<<<M_ROWS, 256, 0, stream>>>(x, grid, bw, sw, sc, out);
  }
}

// Round 2
// 272.316 us; speedup vs baseline: 1.4514x; 1.4514x over previous
//
#include <hip/hip_runtime.h>
#include <hip/hip_bf16.h>

#define IN_F 1024
#define OUT_F 1024
#define KTOT (IN_F * 9)   // 9216: channel-major, k = c*1024 + i, c=0 is silu
#define M_ROWS 8192

typedef short bf16x8 __attribute__((ext_vector_type(8)));
typedef float f32x4 __attribute__((ext_vector_type(4)));

#define AS1 __attribute__((address_space(1)))
#define AS3 __attribute__((address_space(3)))

// ---------------------------------------------------------------- basis eval
// Cox-de Boor with hoisted reciprocals (denominators depend only on the grid
// row, shared by all 8 features a thread handles).
__device__ __forceinline__ void kan_basis_fast(
    float xv, const float* __restrict__ g,
    const float* __restrict__ inv1, const float* __restrict__ inv2,
    const float* __restrict__ inv3, float* __restrict__ out) {
  float b[11];
#pragma unroll
  for (int j = 0; j < 11; ++j)
    b[j] = (xv >= g[j] && xv < g[j + 1]) ? 1.0f : 0.0f;
#pragma unroll
  for (int j = 0; j < 10; ++j)
    b[j] = (xv - g[j]) * inv1[j] * b[j] + (g[j + 2] - xv) * inv1[j + 1] * b[j + 1];
#pragma unroll
  for (int j = 0; j < 9; ++j)
    b[j] = (xv - g[j]) * inv2[j] * b[j] + (g[j + 3] - xv) * inv2[j + 1] * b[j + 1];
#pragma unroll
  for (int j = 0; j < 8; ++j)
    b[j] = (xv - g[j]) * inv3[j] * b[j] + (g[j + 4] - xv) * inv3[j + 1] * b[j + 1];
#pragma unroll
  for (int j = 0; j < 8; ++j) out[j] = b[j];
}

// ------------------------------------------------- A expansion (fp32 -> bf16)
// One thread per (row n, 8 consecutive features i0..i0+7). Writes 9 x 16B
// vectors (silu + 8 basis channels), each wave-coalesced to 1 KiB.
__global__ __launch_bounds__(256) void expand_a(
    const float* __restrict__ x, const float* __restrict__ grid,
    __hip_bfloat16* __restrict__ A, int row0, int nrows) {
  int t = blockIdx.x * 256 + threadIdx.x;
  int n = t >> 7;                  // 128 threads per row
  if (n >= nrows) return;
  int i0 = (t & 127) * 8;

  float g[12];
  const float* gp = grid + (size_t)i0 * 12;   // rows identical by construction
#pragma unroll
  for (int j = 0; j < 12; ++j) g[j] = gp[j];
  float inv1[11], inv2[10], inv3[9];
#pragma unroll
  for (int j = 0; j < 11; ++j) inv1[j] = 1.0f / (g[j + 1] - g[j]);
#pragma unroll
  for (int j = 0; j < 10; ++j) inv2[j] = 1.0f / (g[j + 2] - g[j]);
#pragma unroll
  for (int j = 0; j < 9; ++j)  inv3[j] = 1.0f / (g[j + 3] - g[j]);

  const float* xp = x + (size_t)(row0 + n) * IN_F + i0;
  float xs[8];
  *(f32x4*)&xs[0] = *(const f32x4*)xp;
  *(f32x4*)&xs[4] = *(const f32x4*)(xp + 4);

  bf16x8 out[9];
#pragma unroll
  for (int j = 0; j < 8; ++j) {
    float xv = xs[j];
    float bas[8];
    kan_basis_fast(xv, g, inv1, inv2, inv3, bas);
    float s = xv / (1.0f + __expf(-xv));
    out[0][j] = (short)__bfloat16_as_ushort(__float2bfloat16(s));
#pragma unroll
    for (int c = 0; c < 8; ++c)
      out[c + 1][j] = (short)__bfloat16_as_ushort(__float2bfloat16(bas[c]));
  }
  __hip_bfloat16* dst = A + (size_t)n * KTOT + i0;
#pragma unroll
  for (int c = 0; c < 9; ++c)
    *(bf16x8*)(dst + (size_t)c * IN_F) = out[c];
}

// --------------------------------------------------- B packing (fp32 -> bf16)
__global__ __launch_bounds__(256) void pack_b(
    const float* __restrict__ bw, const float* __restrict__ sw,
    const float* __restrict__ sc, __hip_bfloat16* __restrict__ B) {
  int t = blockIdx.x * 256 + threadIdx.x;   // one per (o, i0/8): 1024*128
  if (t >= OUT_F * 128) return;
  int o = t >> 7;
  int i0 = (t & 127) * 8;

  float bwv[8], scv[8];
  const float* bp = bw + (size_t)o * IN_F + i0;
  const float* sp = sc + (size_t)o * IN_F + i0;
  *(f32x4*)&bwv[0] = *(const f32x4*)bp;
  *(f32x4*)&bwv[4] = *(const f32x4*)(bp + 4);
  *(f32x4*)&scv[0] = *(const f32x4*)sp;
  *(f32x4*)&scv[4] = *(const f32x4*)(sp + 4);

  bf16x8 out[9];
#pragma unroll
  for (int j = 0; j < 8; ++j) {
    out[0][j] = (short)__bfloat16_as_ushort(__float2bfloat16(bwv[j]));
    const float* swp = sw + ((size_t)o * IN_F + i0 + j) * 8;
    float swv[8];
    *(f32x4*)&swv[0] = *(const f32x4*)swp;
    *(f32x4*)&swv[4] = *(const f32x4*)(swp + 4);
#pragma unroll
    for (int c = 0; c < 8; ++c)
      out[c + 1][j] = (short)__bfloat16_as_ushort(__float2bfloat16(swv[c] * scv[j]));
  }
  __hip_bfloat16* dst = B + (size_t)o * KTOT + i0;
#pragma unroll
  for (int c = 0; c < 9; ++c)
    *(bf16x8*)(dst + (size_t)c * IN_F) = out[c];
}

// -------------------------------------------------------------- bf16 GEMM BT
// C(M x 1024) = A(M x K) * B(1024 x K)^T ; m97-structure: 128x128 tile, BK=64
// + T1 bijective XCD swizzle: the 8 bn-blocks sharing an A-panel land on one XCD
#define BM 128
#define BN 128
#define BK 64

__device__ __forceinline__ void gld16(const __hip_bfloat16* g, __hip_bfloat16* l) {
  __builtin_amdgcn_global_load_lds((AS1 void*)g, (AS3 void*)l, 16, 0, 0);
}

__global__ __launch_bounds__(256, 2) void gemm_bt(
    const __hip_bfloat16* __restrict__ A, const __hip_bfloat16* __restrict__ B,
    float* __restrict__ C, int M, int K) {
  __shared__ __align__(16) __hip_bfloat16 As[BM * BK];
  __shared__ __align__(16) __hip_bfloat16 Bs[BN * BK];

  // XCD-aware swizzle: nwg = (M/128)*8, always %8 == 0 here.
  const int nwg = gridDim.x;
  const int q = nwg >> 3;               // blocks per XCD
  const int xcd = blockIdx.x & 7;
  const int lid = blockIdx.x >> 3;
  const int L = xcd * q + lid;          // bijective; same-XCD blocks consecutive
  const int bm = L >> 3;                // 8 consecutive L share bm -> A-panel L2 reuse
  const int bn = L & 7;

  const int tid = threadIdx.x;
  const int lane = tid & 63;
  const int wv = tid >> 6;
  const int wm = wv >> 1, wn = wv & 1;
  const int l15 = lane & 15, lhi = lane >> 4;

  f32x4 acc[4][4];
#pragma unroll
  for (int m = 0; m < 4; ++m)
#pragma unroll
    for (int n = 0; n < 4; ++n) acc[m][n] = f32x4{0.f, 0.f, 0.f, 0.f};

  int arow[4], ac8[4];
#pragma unroll
  for (int j = 0; j < 4; ++j) {
    int chunk = (wv * 4 + j) * 64 + lane;
    arow[j] = chunk >> 3;
    ac8[j] = chunk & 7;
  }

  for (int k0 = 0; k0 < K; k0 += BK) {
#pragma unroll
    for (int j = 0; j < 4; ++j) {
      int op = wv * 4 + j;
      gld16(A + (size_t)(bm * BM + arow[j]) * K + k0 + ac8[j] * 8, As + op * 512);
      gld16(B + (size_t)(bn * BN + arow[j]) * K + k0 + ac8[j] * 8, Bs + op * 512);
    }
    __syncthreads();
#pragma unroll
    for (int kk = 0; kk < 2; ++kk) {
      bf16x8 af[4], bfr[4];
#pragma unroll
      for (int m = 0; m < 4; ++m)
        af[m] = *(const bf16x8*)(&As[(wm * 64 + m * 16 + l15) * BK + kk * 32 + lhi * 8]);
#pragma unroll
      for (int n = 0; n < 4; ++n)
        bfr[n] = *(const bf16x8*)(&Bs[(wn * 64 + n * 16 + l15) * BK + kk * 32 + lhi * 8]);
#pragma unroll
      for (int m = 0; m < 4; ++m)
#pragma unroll
        for (int n = 0; n < 4; ++n)
          acc[m][n] = __builtin_amdgcn_mfma_f32_16x16x32_bf16(af[m], bfr[n], acc[m][n], 0, 0, 0);
    }
    __syncthreads();
  }

#pragma unroll
  for (int m = 0; m < 4; ++m)
#pragma unroll
    for (int n = 0; n < 4; ++n) {
      int col = bn * BN + wn * 64 + n * 16 + l15;
      int row0 = bm * BM + wm * 64 + m * 16 + lhi * 4;
#pragma unroll
      for (int j = 0; j < 4; ++j)
        C[(size_t)(row0 + j) * OUT_F + col] = acc[m][n][j];
    }
}

// ------------------------------------------------ naive fallback (insurance)
__global__ __launch_bounds__(256) void kan_naive(
    const float* __restrict__ x, const float* __restrict__ grid,
    const float* __restrict__ bw, const float* __restrict__ sw,
    const float* __restrict__ sc, float* __restrict__ out) {
  __shared__ float s_act[IN_F];
  __shared__ float s_bas[IN_F * 8];
  int n = blockIdx.x;
  for (int i = threadIdx.x; i < IN_F; i += 256) {
    float xv = x[(size_t)n * IN_F + i];
    float g[12];
    const float* gp = grid + i * 12;
#pragma unroll
    for (int t = 0; t < 12; ++t) g[t] = gp[t];
    float b[11];
#pragma unroll
    for (int j = 0; j < 11; ++j)
      b[j] = (xv >= g[j] && xv < g[j + 1]) ? 1.0f : 0.0f;
#pragma unroll
    for (int k = 1; k <= 3; ++k)
#pragma unroll
      for (int j = 0; j < 11 - k; ++j) {
        float left = (xv - g[j]) / (g[j + k] - g[j]);
        float right = (g[j + k + 1] - xv) / (g[j + k + 1] - g[j + 1]);
        b[j] = left * b[j] + right * b[j + 1];
      }
    s_act[i] = xv / (1.0f + __expf(-xv));
#pragma unroll
    for (int c = 0; c < 8; ++c) s_bas[i * 8 + c] = b[c];
  }
  __syncthreads();
  for (int o = threadIdx.x; o < OUT_F; o += 256) {
    float acc = 0.f;
    const float* bwo = bw + (size_t)o * IN_F;
    const float* swo = sw + (size_t)o * IN_F * 8;
    const float* sco = sc + (size_t)o * IN_F;
    for (int i = 0; i < IN_F; ++i) {
      acc += s_act[i] * bwo[i];
      float p = 0.f;
#pragma unroll
      for (int c = 0; c < 8; ++c) p += s_bas[i * 8 + c] * swo[i * 8 + c];
      acc += p * sco[i];
    }
    out[(size_t)n * OUT_F + o] = acc;
  }
}

// ---------------------------------------------------------------- launch
extern "C" void kernel_launch(void* const* d_in, const int* in_sizes, int n_in,
                              void* d_out, int out_size, void* d_ws, size_t ws_size,
                              hipStream_t stream) {
  const float* x  = (const float*)d_in[0];
  const float* grid = (const float*)d_in[1];
  const float* bw = (const float*)d_in[2];
  const float* sw = (const float*)d_in[3];
  const float* sc = (const float*)d_in[4];
  float* out = (float*)d_out;

  const size_t Bbytes = (size_t)OUT_F * KTOT * 2;   // 18.9 MB
  const size_t rowBytes = (size_t)KTOT * 2;         // 18 KB / A-row

  if (ws_size >= Bbytes + 128 * rowBytes) {
    __hip_bfloat16* Bp = (__hip_bfloat16*)d_ws;
    __hip_bfloat16* Ap = (__hip_bfloat16*)((char*)d_ws + Bbytes);
    size_t arows = (ws_size - Bbytes) / rowBytes;
    int chunk = (int)((arows / 128) * 128);
    if (chunk > M_ROWS) chunk = M_ROWS;

    pack_b<<<OUT_F * 128 / 256, 256, 0, stream>>>(bw, sw, sc, Bp);
    for (int r0 = 0; r0 < M_ROWS; r0 += chunk) {
      int rows = M_ROWS - r0 < chunk ? M_ROWS - r0 : chunk;   // multiple of 128
      expand_a<<<(rows * 128 + 255) / 256, 256, 0, stream>>>(x, grid, Ap, r0, rows);
      gemm_bt<<<(rows / BM) * 8, 256, 0, stream>>>(Ap, Bp, out + (size_t)r0 * OUT_F,
                                                   rows, KTOT);
    }
  } else {
    kan_naive<<<M_ROWS, 256, 0, stream>>>(x, grid, bw, sw, sc, out);
  }
}

// Round 3
// 254.242 us; speedup vs baseline: 1.5546x; 1.0711x over previous
//
#include <hip/hip_runtime.h>
#include <hip/hip_bf16.h>

#define IN_F 1024
#define OUT_F 1024
#define KTOT (IN_F * 9)   // 9216: channel-major, k = c*1024 + i, c=0 is silu
#define M_ROWS 8192

#define BM 256
#define BN 128
#define BK 64
#define NT (KTOT / BK)    // 144 K-tiles

typedef short bf16x8 __attribute__((ext_vector_type(8)));
typedef float f32x4 __attribute__((ext_vector_type(4)));

#define AS1 __attribute__((address_space(1)))
#define AS3 __attribute__((address_space(3)))

// ---------------------------------------------------------------- basis eval
__device__ __forceinline__ void kan_basis_fast(
    float xv, const float* __restrict__ g,
    const float* __restrict__ inv1, const float* __restrict__ inv2,
    const float* __restrict__ inv3, float* __restrict__ out) {
  float b[11];
#pragma unroll
  for (int j = 0; j < 11; ++j)
    b[j] = (xv >= g[j] && xv < g[j + 1]) ? 1.0f : 0.0f;
#pragma unroll
  for (int j = 0; j < 10; ++j)
    b[j] = (xv - g[j]) * inv1[j] * b[j] + (g[j + 2] - xv) * inv1[j + 1] * b[j + 1];
#pragma unroll
  for (int j = 0; j < 9; ++j)
    b[j] = (xv - g[j]) * inv2[j] * b[j] + (g[j + 3] - xv) * inv2[j + 1] * b[j + 1];
#pragma unroll
  for (int j = 0; j < 8; ++j)
    b[j] = (xv - g[j]) * inv3[j] * b[j] + (g[j + 4] - xv) * inv3[j + 1] * b[j + 1];
#pragma unroll
  for (int j = 0; j < 8; ++j) out[j] = b[j];
}

// ------------------------------------------------- A expansion (fp32 -> bf16)
__global__ __launch_bounds__(256) void expand_a(
    const float* __restrict__ x, const float* __restrict__ grid,
    __hip_bfloat16* __restrict__ A, int row0, int nrows) {
  int t = blockIdx.x * 256 + threadIdx.x;
  int n = t >> 7;                  // 128 threads per row
  if (n >= nrows) return;
  int i0 = (t & 127) * 8;

  float g[12];
  const float* gp = grid + (size_t)i0 * 12;   // rows identical by construction
#pragma unroll
  for (int j = 0; j < 12; ++j) g[j] = gp[j];
  float inv1[11], inv2[10], inv3[9];
#pragma unroll
  for (int j = 0; j < 11; ++j) inv1[j] = 1.0f / (g[j + 1] - g[j]);
#pragma unroll
  for (int j = 0; j < 10; ++j) inv2[j] = 1.0f / (g[j + 2] - g[j]);
#pragma unroll
  for (int j = 0; j < 9; ++j)  inv3[j] = 1.0f / (g[j + 3] - g[j]);

  const float* xp = x + (size_t)(row0 + n) * IN_F + i0;
  float xs[8];
  *(f32x4*)&xs[0] = *(const f32x4*)xp;
  *(f32x4*)&xs[4] = *(const f32x4*)(xp + 4);

  bf16x8 out[9];
#pragma unroll
  for (int j = 0; j < 8; ++j) {
    float xv = xs[j];
    float bas[8];
    kan_basis_fast(xv, g, inv1, inv2, inv3, bas);
    float s = xv / (1.0f + __expf(-xv));
    out[0][j] = (short)__bfloat16_as_ushort(__float2bfloat16(s));
#pragma unroll
    for (int c = 0; c < 8; ++c)
      out[c + 1][j] = (short)__bfloat16_as_ushort(__float2bfloat16(bas[c]));
  }
  __hip_bfloat16* dst = A + (size_t)n * KTOT + i0;
#pragma unroll
  for (int c = 0; c < 9; ++c)
    *(bf16x8*)(dst + (size_t)c * IN_F) = out[c];
}

// --------------------------------------------------- B packing (fp32 -> bf16)
__global__ __launch_bounds__(256) void pack_b(
    const float* __restrict__ bw, const float* __restrict__ sw,
    const float* __restrict__ sc, __hip_bfloat16* __restrict__ B) {
  int t = blockIdx.x * 256 + threadIdx.x;   // one per (o, i0/8): 1024*128
  if (t >= OUT_F * 128) return;
  int o = t >> 7;
  int i0 = (t & 127) * 8;

  float bwv[8], scv[8];
  const float* bp = bw + (size_t)o * IN_F + i0;
  const float* sp = sc + (size_t)o * IN_F + i0;
  *(f32x4*)&bwv[0] = *(const f32x4*)bp;
  *(f32x4*)&bwv[4] = *(const f32x4*)(bp + 4);
  *(f32x4*)&scv[0] = *(const f32x4*)sp;
  *(f32x4*)&scv[4] = *(const f32x4*)(sp + 4);

  bf16x8 out[9];
#pragma unroll
  for (int j = 0; j < 8; ++j) {
    out[0][j] = (short)__bfloat16_as_ushort(__float2bfloat16(bwv[j]));
    const float* swp = sw + ((size_t)o * IN_F + i0 + j) * 8;
    float swv[8];
    *(f32x4*)&swv[0] = *(const f32x4*)swp;
    *(f32x4*)&swv[4] = *(const f32x4*)(swp + 4);
#pragma unroll
    for (int c = 0; c < 8; ++c)
      out[c + 1][j] = (short)__bfloat16_as_ushort(__float2bfloat16(swv[c] * scv[j]));
  }
  __hip_bfloat16* dst = B + (size_t)o * KTOT + i0;
#pragma unroll
  for (int c = 0; c < 9; ++c)
    *(bf16x8*)(dst + (size_t)c * IN_F) = out[c];
}

// -------------------------------------------------------------- bf16 GEMM BT
// 256x128 tile, BK=64, 8 waves (wave tile 64x64), 3-deep LDS ring staged 2
// ahead via global_load_lds, counted vmcnt(6), 4 phases/tile, T2 XOR swizzle
// (both-sides: pre-swizzled global src + swizzled ds_read, LDS linear).

__device__ __forceinline__ void gld16(const __hip_bfloat16* g, __hip_bfloat16* l) {
  __builtin_amdgcn_global_load_lds((AS1 void*)g, (AS3 void*)l, 16, 0, 0);
}

#define MFMA16(d, a, b) d = __builtin_amdgcn_mfma_f32_16x16x32_bf16(a, b, d, 0, 0, 0)

// one phase: A-frags for row-block mm (both k-halves), 8 MFMAs, setprio-wrapped
#define PHASE_M(mm) do {                                         \
    bf16x8 a0 = *(const bf16x8*)(as_ + aOff[mm][0]);             \
    bf16x8 a1 = *(const bf16x8*)(as_ + aOff[mm][1]);             \
    __builtin_amdgcn_s_setprio(1);                               \
    MFMA16(acc[mm][0], a0, bf_[0][0]); MFMA16(acc[mm][0], a1, bf_[0][1]); \
    MFMA16(acc[mm][1], a0, bf_[1][0]); MFMA16(acc[mm][1], a1, bf_[1][1]); \
    MFMA16(acc[mm][2], a0, bf_[2][0]); MFMA16(acc[mm][2], a1, bf_[2][1]); \
    MFMA16(acc[mm][3], a0, bf_[3][0]); MFMA16(acc[mm][3], a1, bf_[3][1]); \
    __builtin_amdgcn_s_setprio(0);                               \
  } while (0)

#define LOAD_BF() do {                                           \
    _Pragma("unroll")                                            \
    for (int n = 0; n < 4; ++n) {                                \
      bf_[n][0] = *(const bf16x8*)(bs_ + bOff[n][0]);            \
      bf_[n][1] = *(const bf16x8*)(bs_ + bOff[n][1]);            \
    }                                                            \
  } while (0)

__global__ __launch_bounds__(512, 2) void gemm_8ph(
    const __hip_bfloat16* __restrict__ A, const __hip_bfloat16* __restrict__ B,
    float* __restrict__ C) {
  __shared__ __align__(16) __hip_bfloat16 As[3][BM * BK];  // 3 x 32 KB
  __shared__ __align__(16) __hip_bfloat16 Bs[3][BN * BK];  // 3 x 16 KB

  // T1 bijective XCD swizzle: 8 bn-blocks sharing an A-panel on one XCD
  const int nwg = gridDim.x;            // (M/256)*8, %8 == 0
  const int q = nwg >> 3;
  const int L = (blockIdx.x & 7) * q + (blockIdx.x >> 3);
  const int bm = L >> 3, bn = L & 7;

  const int tid = threadIdx.x;
  const int lane = tid & 63;
  const int wv = tid >> 6;            // 0..7
  const int wm = wv >> 1;             // 0..3 (64-row group)
  const int wn = wv & 1;              // 0..1 (64-col group)
  const int l15 = lane & 15, lhi = lane >> 4;
  const int K = KTOT;

  // ---- staging: per-wave global_load_lds; LDS linear, source pre-swizzled.
  // chunk p (16B) at LDS pos p holds global chunk (row=p>>3, (p&7)^(row&7)).
  const __hip_bfloat16* aSrc[4];
  const __hip_bfloat16* bSrc[2];
  int aDst[4], bDst[2];
#pragma unroll
  for (int j = 0; j < 4; ++j) {
    int p = j * 512 + wv * 64 + lane;
    int row = p >> 3;
    int col = (p & 7) ^ (row & 7);
    aSrc[j] = A + (size_t)(bm * BM + row) * K + col * 8;
    aDst[j] = (j * 512 + wv * 64) * 8;
  }
#pragma unroll
  for (int j = 0; j < 2; ++j) {
    int p = j * 512 + wv * 64 + lane;
    int row = p >> 3;
    int col = (p & 7) ^ (row & 7);
    bSrc[j] = B + (size_t)(bn * BN + row) * K + col * 8;
    bDst[j] = (j * 512 + wv * 64) * 8;
  }

  // ---- fragment ds_read offsets (swizzled): row*64 + ((kk*4+lhi)^(l15&7))*8
  int aOff[4][2], bOff[4][2];
#pragma unroll
  for (int m = 0; m < 4; ++m)
#pragma unroll
    for (int kk = 0; kk < 2; ++kk) {
      int rowA = wm * 64 + m * 16 + l15;
      aOff[m][kk] = rowA * 64 + (((kk * 4 + lhi) ^ (l15 & 7)) * 8);
      int rowB = wn * 64 + m * 16 + l15;
      bOff[m][kk] = rowB * 64 + (((kk * 4 + lhi) ^ (l15 & 7)) * 8);
    }

  f32x4 acc[4][4];
#pragma unroll
  for (int m = 0; m < 4; ++m)
#pragma unroll
    for (int n = 0; n < 4; ++n) acc[m][n] = f32x4{0.f, 0.f, 0.f, 0.f};

  // ---- prologue: stage tiles 0 and 1 (6 wave-ops each)
#pragma unroll
  for (int j = 0; j < 4; ++j) gld16(aSrc[j], &As[0][0] + aDst[j]);
#pragma unroll
  for (int j = 0; j < 2; ++j) gld16(bSrc[j], &Bs[0][0] + bDst[j]);
#pragma unroll
  for (int j = 0; j < 4; ++j) gld16(aSrc[j] + BK, &As[1][0] + aDst[j]);
#pragma unroll
  for (int j = 0; j < 2; ++j) gld16(bSrc[j] + BK, &Bs[1][0] + bDst[j]);

  int cur = 0, stg = 2;
  for (int t = 0; t < NT - 2; ++t) {
    const __hip_bfloat16* as_ = &As[cur][0];
    const __hip_bfloat16* bs_ = &Bs[cur][0];
    __hip_bfloat16* asD = &As[stg][0];
    __hip_bfloat16* bsD = &Bs[stg][0];
    const int kt2 = (t + 2) * BK;

    asm volatile("s_waitcnt vmcnt(6)" ::: "memory");  // tile t landed
    __builtin_amdgcn_s_barrier();                     // entry = hazard fence
    asm volatile("" ::: "memory");

    bf16x8 bf_[4][2];
    // ph0: stage A half 0 of tile t+2 ; all B-frags ; MFMA m=0
    gld16(aSrc[0] + kt2, asD + aDst[0]);
    gld16(aSrc[1] + kt2, asD + aDst[1]);
    LOAD_BF();
    PHASE_M(0);
    __builtin_amdgcn_sched_barrier(0);
    // ph1: stage A half 1 ; MFMA m=1
    gld16(aSrc[2] + kt2, asD + aDst[2]);
    gld16(aSrc[3] + kt2, asD + aDst[3]);
    PHASE_M(1);
    __builtin_amdgcn_sched_barrier(0);
    // ph2: stage B half 0 ; MFMA m=2
    gld16(bSrc[0] + kt2, bsD + bDst[0]);
    PHASE_M(2);
    __builtin_amdgcn_sched_barrier(0);
    // ph3: stage B half 1 ; MFMA m=3
    gld16(bSrc[1] + kt2, bsD + bDst[1]);
    PHASE_M(3);
    __builtin_amdgcn_sched_barrier(0);

    cur = cur == 2 ? 0 : cur + 1;
    stg = stg == 2 ? 0 : stg + 1;
  }
  // peeled iter NT-2: only tiles NT-2, NT-1 outstanding -> vmcnt(6)
  {
    const __hip_bfloat16* as_ = &As[cur][0];
    const __hip_bfloat16* bs_ = &Bs[cur][0];
    asm volatile("s_waitcnt vmcnt(6)" ::: "memory");
    __builtin_amdgcn_s_barrier();
    asm volatile("" ::: "memory");
    bf16x8 bf_[4][2];
    LOAD_BF();
    PHASE_M(0); PHASE_M(1); PHASE_M(2); PHASE_M(3);
    cur = cur == 2 ? 0 : cur + 1;
  }
  // peeled iter NT-1: drain
  {
    const __hip_bfloat16* as_ = &As[cur][0];
    const __hip_bfloat16* bs_ = &Bs[cur][0];
    asm volatile("s_waitcnt vmcnt(0)" ::: "memory");
    __builtin_amdgcn_s_barrier();
    asm volatile("" ::: "memory");
    bf16x8 bf_[4][2];
    LOAD_BF();
    PHASE_M(0); PHASE_M(1); PHASE_M(2); PHASE_M(3);
  }

  // epilogue: C/D mapping col = lane&15, row = (lane>>4)*4 + reg [m89]
#pragma unroll
  for (int m = 0; m < 4; ++m)
#pragma unroll
    for (int n = 0; n < 4; ++n) {
      int col = bn * BN + wn * 64 + n * 16 + l15;
      int row0 = bm * BM + wm * 64 + m * 16 + lhi * 4;
#pragma unroll
      for (int j = 0; j < 4; ++j)
        C[(size_t)(row0 + j) * OUT_F + col] = acc[m][n][j];
    }
}

// ------------------------------------------------ naive fallback (insurance)
__global__ __launch_bounds__(256) void kan_naive(
    const float* __restrict__ x, const float* __restrict__ grid,
    const float* __restrict__ bw, const float* __restrict__ sw,
    const float* __restrict__ sc, float* __restrict__ out) {
  __shared__ float s_act[IN_F];
  __shared__ float s_bas[IN_F * 8];
  int n = blockIdx.x;
  for (int i = threadIdx.x; i < IN_F; i += 256) {
    float xv = x[(size_t)n * IN_F + i];
    float g[12];
    const float* gp = grid + i * 12;
#pragma unroll
    for (int t = 0; t < 12; ++t) g[t] = gp[t];
    float b[11];
#pragma unroll
    for (int j = 0; j < 11; ++j)
      b[j] = (xv >= g[j] && xv < g[j + 1]) ? 1.0f : 0.0f;
#pragma unroll
    for (int k = 1; k <= 3; ++k)
#pragma unroll
      for (int j = 0; j < 11 - k; ++j) {
        float left = (xv - g[j]) / (g[j + k] - g[j]);
        float right = (g[j + k + 1] - xv) / (g[j + k + 1] - g[j + 1]);
        b[j] = left * b[j] + right * b[j + 1];
      }
    s_act[i] = xv / (1.0f + __expf(-xv));
#pragma unroll
    for (int c = 0; c < 8; ++c) s_bas[i * 8 + c] = b[c];
  }
  __syncthreads();
  for (int o = threadIdx.x; o < OUT_F; o += 256) {
    float acc = 0.f;
    const float* bwo = bw + (size_t)o * IN_F;
    const float* swo = sw + (size_t)o * IN_F * 8;
    const float* sco = sc + (size_t)o * IN_F;
    for (int i = 0; i < IN_F; ++i) {
      acc += s_act[i] * bwo[i];
      float p = 0.f;
#pragma unroll
      for (int c = 0; c < 8; ++c) p += s_bas[i * 8 + c] * swo[i * 8 + c];
      acc += p * sco[i];
    }
    out[(size_t)n * OUT_F + o] = acc;
  }
}

// ---------------------------------------------------------------- launch
extern "C" void kernel_launch(void* const* d_in, const int* in_sizes, int n_in,
                              void* d_out, int out_size, void* d_ws, size_t ws_size,
                              hipStream_t stream) {
  const float* x  = (const float*)d_in[0];
  const float* grid = (const float*)d_in[1];
  const float* bw = (const float*)d_in[2];
  const float* sw = (const float*)d_in[3];
  const float* sc = (const float*)d_in[4];
  float* out = (float*)d_out;

  const size_t Bbytes = (size_t)OUT_F * KTOT * 2;   // 18.9 MB
  const size_t rowBytes = (size_t)KTOT * 2;         // 18 KB / A-row

  if (ws_size >= Bbytes + 256 * rowBytes) {
    __hip_bfloat16* Bp = (__hip_bfloat16*)d_ws;
    __hip_bfloat16* Ap = (__hip_bfloat16*)((char*)d_ws + Bbytes);
    size_t arows = (ws_size - Bbytes) / rowBytes;
    int chunk = (int)((arows / 256) * 256);
    if (chunk > M_ROWS) chunk = M_ROWS;

    pack_b<<<OUT_F * 128 / 256, 256, 0, stream>>>(bw, sw, sc, Bp);
    for (int r0 = 0; r0 < M_ROWS; r0 += chunk) {
      int rows = M_ROWS - r0 < chunk ? M_ROWS - r0 : chunk;   // multiple of 256
      expand_a<<<(rows * 128 + 255) / 256, 256, 0, stream>>>(x, grid, Ap, r0, rows);
      gemm_8ph<<<(rows / BM) * 8, 512, 0, stream>>>(Ap, Bp, out + (size_t)r0 * OUT_F);
    }
  } else {
    kan_naive<<<M_ROWS, 256, 0, stream>>>(x, grid, bw, sw, sc, out);
  }
}

// Round 4
// 196.100 us; speedup vs baseline: 2.0155x; 1.2965x over previous
//
#include <hip/hip_runtime.h>
#include <hip/hip_bf16.h>

#define IN_F 1024
#define OUT_F 1024
#define KTOT (IN_F * 9)   // 9216: channel-major, k = c*1024 + i, c=0 is silu
#define M_ROWS 8192

#define BM 256
#define BN 128
#define BK 64
#define NT (KTOT / BK)    // 144 K-tiles

typedef short bf16x8 __attribute__((ext_vector_type(8)));
typedef int   i32x4  __attribute__((ext_vector_type(4)));
typedef float f32x4  __attribute__((ext_vector_type(4)));

#define AS1 __attribute__((address_space(1)))
#define AS3 __attribute__((address_space(3)))

// ---------------------------------------------------------------- basis eval
__device__ __forceinline__ void kan_basis_fast(
    float xv, const float* __restrict__ g,
    const float* __restrict__ inv1, const float* __restrict__ inv2,
    const float* __restrict__ inv3, float* __restrict__ out) {
  float b[11];
#pragma unroll
  for (int j = 0; j < 11; ++j)
    b[j] = (xv >= g[j] && xv < g[j + 1]) ? 1.0f : 0.0f;
#pragma unroll
  for (int j = 0; j < 10; ++j)
    b[j] = (xv - g[j]) * inv1[j] * b[j] + (g[j + 2] - xv) * inv1[j + 1] * b[j + 1];
#pragma unroll
  for (int j = 0; j < 9; ++j)
    b[j] = (xv - g[j]) * inv2[j] * b[j] + (g[j + 3] - xv) * inv2[j + 1] * b[j + 1];
#pragma unroll
  for (int j = 0; j < 8; ++j)
    b[j] = (xv - g[j]) * inv3[j] * b[j] + (g[j + 4] - xv) * inv3[j + 1] * b[j + 1];
#pragma unroll
  for (int j = 0; j < 8; ++j) out[j] = b[j];
}

// ------------------------------------------------- A expansion (fp32 -> bf16)
__global__ __launch_bounds__(256) void expand_a(
    const float* __restrict__ x, const float* __restrict__ grid,
    __hip_bfloat16* __restrict__ A, int row0, int nrows) {
  int t = blockIdx.x * 256 + threadIdx.x;
  int n = t >> 7;                  // 128 threads per row
  if (n >= nrows) return;
  int i0 = (t & 127) * 8;

  float g[12];
  const float* gp = grid + (size_t)i0 * 12;   // rows identical by construction
#pragma unroll
  for (int j = 0; j < 12; ++j) g[j] = gp[j];
  float inv1[11], inv2[10], inv3[9];
#pragma unroll
  for (int j = 0; j < 11; ++j) inv1[j] = 1.0f / (g[j + 1] - g[j]);
#pragma unroll
  for (int j = 0; j < 10; ++j) inv2[j] = 1.0f / (g[j + 2] - g[j]);
#pragma unroll
  for (int j = 0; j < 9; ++j)  inv3[j] = 1.0f / (g[j + 3] - g[j]);

  const float* xp = x + (size_t)(row0 + n) * IN_F + i0;
  float xs[8];
  *(f32x4*)&xs[0] = *(const f32x4*)xp;
  *(f32x4*)&xs[4] = *(const f32x4*)(xp + 4);

  bf16x8 out[9];
#pragma unroll
  for (int j = 0; j < 8; ++j) {
    float xv = xs[j];
    float bas[8];
    kan_basis_fast(xv, g, inv1, inv2, inv3, bas);
    float s = xv / (1.0f + __expf(-xv));
    out[0][j] = (short)__bfloat16_as_ushort(__float2bfloat16(s));
#pragma unroll
    for (int c = 0; c < 8; ++c)
      out[c + 1][j] = (short)__bfloat16_as_ushort(__float2bfloat16(bas[c]));
  }
  __hip_bfloat16* dst = A + (size_t)n * KTOT + i0;
#pragma unroll
  for (int c = 0; c < 9; ++c)
    *(bf16x8*)(dst + (size_t)c * IN_F) = out[c];
}

// --------------------------------------------------- B packing (fp32 -> bf16)
__global__ __launch_bounds__(256) void pack_b(
    const float* __restrict__ bw, const float* __restrict__ sw,
    const float* __restrict__ sc, __hip_bfloat16* __restrict__ B) {
  int t = blockIdx.x * 256 + threadIdx.x;   // one per (o, i0/8): 1024*128
  if (t >= OUT_F * 128) return;
  int o = t >> 7;
  int i0 = (t & 127) * 8;

  float bwv[8], scv[8];
  const float* bp = bw + (size_t)o * IN_F + i0;
  const float* sp = sc + (size_t)o * IN_F + i0;
  *(f32x4*)&bwv[0] = *(const f32x4*)bp;
  *(f32x4*)&bwv[4] = *(const f32x4*)(bp + 4);
  *(f32x4*)&scv[0] = *(const f32x4*)sp;
  *(f32x4*)&scv[4] = *(const f32x4*)(sp + 4);

  bf16x8 out[9];
#pragma unroll
  for (int j = 0; j < 8; ++j) {
    out[0][j] = (short)__bfloat16_as_ushort(__float2bfloat16(bwv[j]));
    const float* swp = sw + ((size_t)o * IN_F + i0 + j) * 8;
    float swv[8];
    *(f32x4*)&swv[0] = *(const f32x4*)swp;
    *(f32x4*)&swv[4] = *(const f32x4*)(swp + 4);
#pragma unroll
    for (int c = 0; c < 8; ++c)
      out[c + 1][j] = (short)__bfloat16_as_ushort(__float2bfloat16(swv[c] * scv[j]));
  }
  __hip_bfloat16* dst = B + (size_t)o * KTOT + i0;
#pragma unroll
  for (int c = 0; c < 9; ++c)
    *(bf16x8*)(dst + (size_t)c * IN_F) = out[c];
}

// -------------------------------------------------------------- bf16 GEMM BT
// 256x128 tile, BK=64, 8 waves (64x64 each). m201-style schedule:
// per K-tile 2 phases (kk halves); phase = {8 asm ds_read_b128, 3 gld16,
// barrier, lgkmcnt(0)+sched_barrier, setprio(1), 16 MFMA, setprio(0),
// barrier}. 3-deep LDS ring staged 2 ahead, counted vmcnt(6) once/tile.
// T2 XOR swizzle both-sides (pre-swizzled global src + swizzled read addr).

__device__ __forceinline__ void gld16(const __hip_bfloat16* g, __hip_bfloat16* l) {
  __builtin_amdgcn_global_load_lds((AS1 void*)g, (AS3 void*)l, 16, 0, 0);
}

// inline-asm LDS read: opaque to alias analysis -> no compiler vmcnt(0) drain
__device__ __forceinline__ bf16x8 dsr128(uint32_t addr) {
  i32x4 r;
  asm volatile("ds_read_b128 %0, %1" : "=v"(r) : "v"(addr));
  return __builtin_bit_cast(bf16x8, r);
}

#define MFMA16(d, a, b) d = __builtin_amdgcn_mfma_f32_16x16x32_bf16(a, b, d, 0, 0, 0)

#define DO_PHASE(kk, STAGE, TAIL) do {                                    \
    bf16x8 a0 = dsr128(aS + aOffB[kk][0]);                                \
    bf16x8 a1 = dsr128(aS + aOffB[kk][1]);                                \
    bf16x8 a2 = dsr128(aS + aOffB[kk][2]);                                \
    bf16x8 a3 = dsr128(aS + aOffB[kk][3]);                                \
    bf16x8 b0 = dsr128(bS + bOffB[kk][0]);                                \
    bf16x8 b1 = dsr128(bS + bOffB[kk][1]);                                \
    bf16x8 b2 = dsr128(bS + bOffB[kk][2]);                                \
    bf16x8 b3 = dsr128(bS + bOffB[kk][3]);                                \
    STAGE                                                                 \
    __builtin_amdgcn_sched_barrier(0);                                    \
    __builtin_amdgcn_s_barrier();                                         \
    asm volatile("s_waitcnt lgkmcnt(0)" ::: "memory");                    \
    __builtin_amdgcn_sched_barrier(0);                                    \
    __builtin_amdgcn_s_setprio(1);                                        \
    MFMA16(acc[0][0], a0, b0); MFMA16(acc[0][1], a0, b1);                 \
    MFMA16(acc[0][2], a0, b2); MFMA16(acc[0][3], a0, b3);                 \
    MFMA16(acc[1][0], a1, b0); MFMA16(acc[1][1], a1, b1);                 \
    MFMA16(acc[1][2], a1, b2); MFMA16(acc[1][3], a1, b3);                 \
    MFMA16(acc[2][0], a2, b0); MFMA16(acc[2][1], a2, b1);                 \
    MFMA16(acc[2][2], a2, b2); MFMA16(acc[2][3], a2, b3);                 \
    MFMA16(acc[3][0], a3, b0); MFMA16(acc[3][1], a3, b1);                 \
    MFMA16(acc[3][2], a3, b2); MFMA16(acc[3][3], a3, b3);                 \
    __builtin_amdgcn_s_setprio(0);                                        \
    __builtin_amdgcn_sched_barrier(0);                                    \
    TAIL                                                                  \
    __builtin_amdgcn_s_barrier();                                         \
    __builtin_amdgcn_sched_barrier(0);                                    \
  } while (0)

__global__ __launch_bounds__(512, 2) void gemm_v4(
    const __hip_bfloat16* __restrict__ A, const __hip_bfloat16* __restrict__ B,
    float* __restrict__ C) {
  __shared__ __align__(16) __hip_bfloat16 As[3][BM * BK];  // 3 x 32 KB
  __shared__ __align__(16) __hip_bfloat16 Bs[3][BN * BK];  // 3 x 16 KB

  // T1 bijective XCD swizzle: 8 bn-blocks sharing an A-panel on one XCD
  const int nwg = gridDim.x;            // (M/256)*8, %8 == 0
  const int q = nwg >> 3;
  const int L = (blockIdx.x & 7) * q + (blockIdx.x >> 3);
  const int bm = L >> 3, bn = L & 7;

  const int tid = threadIdx.x;
  const int lane = tid & 63;
  const int wv = tid >> 6;            // 0..7
  const int wm = wv >> 1;             // 0..3 (64-row group)
  const int wn = wv & 1;              // 0..1 (64-col group)
  const int l15 = lane & 15, lhi = lane >> 4;
  const int K = KTOT;

  // ---- staging: LDS linear, global source pre-swizzled (rule #21).
  // chunk p (16B) at LDS pos p holds global chunk (row=p>>3, (p&7)^(row&7)).
  const __hip_bfloat16* aSrc[4];
  const __hip_bfloat16* bSrc[2];
  int aDst[4], bDst[2];
#pragma unroll
  for (int j = 0; j < 4; ++j) {
    int p = j * 512 + wv * 64 + lane;
    int row = p >> 3;
    int col = (p & 7) ^ (row & 7);
    aSrc[j] = A + (size_t)(bm * BM + row) * K + col * 8;
    aDst[j] = (j * 512 + wv * 64) * 8;
  }
#pragma unroll
  for (int j = 0; j < 2; ++j) {
    int p = j * 512 + wv * 64 + lane;
    int row = p >> 3;
    int col = (p & 7) ^ (row & 7);
    bSrc[j] = B + (size_t)(bn * BN + row) * K + col * 8;
    bDst[j] = (j * 512 + wv * 64) * 8;
  }

  // ---- fragment read byte-offsets (swizzled), per kk half
  const uint32_t aBase = (uint32_t)(uintptr_t)(AS3 const void*)&As[0][0];
  const uint32_t bBase = (uint32_t)(uintptr_t)(AS3 const void*)&Bs[0][0];
  uint32_t aOffB[2][4], bOffB[2][4];
#pragma unroll
  for (int kk = 0; kk < 2; ++kk)
#pragma unroll
    for (int m = 0; m < 4; ++m) {
      int rowA = wm * 64 + m * 16 + l15;
      aOffB[kk][m] = (rowA * 64 + (((kk * 4 + lhi) ^ (l15 & 7)) * 8)) * 2;
      int rowB = wn * 64 + m * 16 + l15;
      bOffB[kk][m] = (rowB * 64 + (((kk * 4 + lhi) ^ (l15 & 7)) * 8)) * 2;
    }

  f32x4 acc[4][4];
#pragma unroll
  for (int m = 0; m < 4; ++m)
#pragma unroll
    for (int n = 0; n < 4; ++n) acc[m][n] = f32x4{0.f, 0.f, 0.f, 0.f};

  // ---- prologue: stage tiles 0 and 1 (6 wave-ops each)
#pragma unroll
  for (int j = 0; j < 4; ++j) gld16(aSrc[j], &As[0][0] + aDst[j]);
#pragma unroll
  for (int j = 0; j < 2; ++j) gld16(bSrc[j], &Bs[0][0] + bDst[j]);
#pragma unroll
  for (int j = 0; j < 4; ++j) gld16(aSrc[j] + BK, &As[1][0] + aDst[j]);
#pragma unroll
  for (int j = 0; j < 2; ++j) gld16(bSrc[j] + BK, &Bs[1][0] + bDst[j]);
  asm volatile("s_waitcnt vmcnt(6)" ::: "memory");   // tile 0 landed
  __builtin_amdgcn_s_barrier();

  int cur = 0, stg = 2;
  for (int t = 0; t < NT - 2; ++t) {
    const uint32_t aS = aBase + (uint32_t)cur * (BM * BK * 2);
    const uint32_t bS = bBase + (uint32_t)cur * (BN * BK * 2);
    __hip_bfloat16* asD = &As[stg][0];
    __hip_bfloat16* bsD = &Bs[stg][0];
    const int kt2 = (t + 2) * BK;

    DO_PHASE(0,
      { gld16(aSrc[0] + kt2, asD + aDst[0]);
        gld16(aSrc[1] + kt2, asD + aDst[1]);
        gld16(aSrc[2] + kt2, asD + aDst[2]); },
      {});
    DO_PHASE(1,
      { gld16(aSrc[3] + kt2, asD + aDst[3]);
        gld16(bSrc[0] + kt2, bsD + bDst[0]);
        gld16(bSrc[1] + kt2, bsD + bDst[1]); },
      { asm volatile("s_waitcnt vmcnt(6)" ::: "memory"); });

    cur = cur == 2 ? 0 : cur + 1;
    stg = stg == 2 ? 0 : stg + 1;
  }
  // t = NT-2: no staging; confirm last tile at phase end
  {
    const uint32_t aS = aBase + (uint32_t)cur * (BM * BK * 2);
    const uint32_t bS = bBase + (uint32_t)cur * (BN * BK * 2);
    DO_PHASE(0, {}, {});
    DO_PHASE(1, {}, { asm volatile("s_waitcnt vmcnt(0)" ::: "memory"); });
    cur = cur == 2 ? 0 : cur + 1;
  }
  // t = NT-1: drain
  {
    const uint32_t aS = aBase + (uint32_t)cur * (BM * BK * 2);
    const uint32_t bS = bBase + (uint32_t)cur * (BN * BK * 2);
    DO_PHASE(0, {}, {});
    DO_PHASE(1, {}, {});
  }

  // epilogue: C/D mapping col = lane&15, row = (lane>>4)*4 + reg [m89]
#pragma unroll
  for (int m = 0; m < 4; ++m)
#pragma unroll
    for (int n = 0; n < 4; ++n) {
      int col = bn * BN + wn * 64 + n * 16 + l15;
      int row0 = bm * BM + wm * 64 + m * 16 + lhi * 4;
#pragma unroll
      for (int j = 0; j < 4; ++j)
        C[(size_t)(row0 + j) * OUT_F + col] = acc[m][n][j];
    }
}

// ------------------------------------------------ naive fallback (insurance)
__global__ __launch_bounds__(256) void kan_naive(
    const float* __restrict__ x, const float* __restrict__ grid,
    const float* __restrict__ bw, const float* __restrict__ sw,
    const float* __restrict__ sc, float* __restrict__ out) {
  __shared__ float s_act[IN_F];
  __shared__ float s_bas[IN_F * 8];
  int n = blockIdx.x;
  for (int i = threadIdx.x; i < IN_F; i += 256) {
    float xv = x[(size_t)n * IN_F + i];
    float g[12];
    const float* gp = grid + i * 12;
#pragma unroll
    for (int t = 0; t < 12; ++t) g[t] = gp[t];
    float b[11];
#pragma unroll
    for (int j = 0; j < 11; ++j)
      b[j] = (xv >= g[j] && xv < g[j + 1]) ? 1.0f : 0.0f;
#pragma unroll
    for (int k = 1; k <= 3; ++k)
#pragma unroll
      for (int j = 0; j < 11 - k; ++j) {
        float left = (xv - g[j]) / (g[j + k] - g[j]);
        float right = (g[j + k + 1] - xv) / (g[j + k + 1] - g[j + 1]);
        b[j] = left * b[j] + right * b[j + 1];
      }
    s_act[i] = xv / (1.0f + __expf(-xv));
#pragma unroll
    for (int c = 0; c < 8; ++c) s_bas[i * 8 + c] = b[c];
  }
  __syncthreads();
  for (int o = threadIdx.x; o < OUT_F; o += 256) {
    float acc = 0.f;
    const float* bwo = bw + (size_t)o * IN_F;
    const float* swo = sw + (size_t)o * IN_F * 8;
    const float* sco = sc + (size_t)o * IN_F;
    for (int i = 0; i < IN_F; ++i) {
      acc += s_act[i] * bwo[i];
      float p = 0.f;
#pragma unroll
      for (int c = 0; c < 8; ++c) p += s_bas[i * 8 + c] * swo[i * 8 + c];
      acc += p * sco[i];
    }
    out[(size_t)n * OUT_F + o] = acc;
  }
}

// ---------------------------------------------------------------- launch
extern "C" void kernel_launch(void* const* d_in, const int* in_sizes, int n_in,
                              void* d_out, int out_size, void* d_ws, size_t ws_size,
                              hipStream_t stream) {
  const float* x  = (const float*)d_in[0];
  const float* grid = (const float*)d_in[1];
  const float* bw = (const float*)d_in[2];
  const float* sw = (const float*)d_in[3];
  const float* sc = (const float*)d_in[4];
  float* out = (float*)d_out;

  const size_t Bbytes = (size_t)OUT_F * KTOT * 2;   // 18.9 MB
  const size_t rowBytes = (size_t)KTOT * 2;         // 18 KB / A-row

  if (ws_size >= Bbytes + 256 * rowBytes) {
    __hip_bfloat16* Bp = (__hip_bfloat16*)d_ws;
    __hip_bfloat16* Ap = (__hip_bfloat16*)((char*)d_ws + Bbytes);
    size_t arows = (ws_size - Bbytes) / rowBytes;
    int chunk = (int)((arows / 256) * 256);
    if (chunk > M_ROWS) chunk = M_ROWS;

    pack_b<<<OUT_F * 128 / 256, 256, 0, stream>>>(bw, sw, sc, Bp);
    for (int r0 = 0; r0 < M_ROWS; r0 += chunk) {
      int rows = M_ROWS - r0 < chunk ? M_ROWS - r0 : chunk;   // multiple of 256
      expand_a<<<(rows * 128 + 255) / 256, 256, 0, stream>>>(x, grid, Ap, r0, rows);
      gemm_v4<<<(rows / BM) * 8, 512, 0, stream>>>(Ap, Bp, out + (size_t)r0 * OUT_F);
    }
  } else {
    kan_naive<<<M_ROWS, 256, 0, stream>>>(x, grid, bw, sw, sc, out);
  }
}

// Round 5
// 188.926 us; speedup vs baseline: 2.0921x; 1.0380x over previous
//
#include <hip/hip_runtime.h>
#include <hip/hip_bf16.h>

#define IN_F 1024
#define OUT_F 1024
#define KTOT (IN_F * 9)   // 9216: channel-major, k = c*1024 + i, c=0 is silu
#define M_ROWS 8192

#define BM 256
#define BN 128
#define BK 64
#define NT (KTOT / BK)    // 144 K-tiles

typedef short bf16x8 __attribute__((ext_vector_type(8)));
typedef int   i32x4  __attribute__((ext_vector_type(4)));
typedef float f32x4  __attribute__((ext_vector_type(4)));

#define AS1 __attribute__((address_space(1)))
#define AS3 __attribute__((address_space(3)))

// ---------------------------------------------------------------- basis eval
__device__ __forceinline__ void kan_basis_fast(
    float xv, const float* __restrict__ g,
    const float* __restrict__ inv1, const float* __restrict__ inv2,
    const float* __restrict__ inv3, float* __restrict__ out) {
  float b[11];
#pragma unroll
  for (int j = 0; j < 11; ++j)
    b[j] = (xv >= g[j] && xv < g[j + 1]) ? 1.0f : 0.0f;
#pragma unroll
  for (int j = 0; j < 10; ++j)
    b[j] = (xv - g[j]) * inv1[j] * b[j] + (g[j + 2] - xv) * inv1[j + 1] * b[j + 1];
#pragma unroll
  for (int j = 0; j < 9; ++j)
    b[j] = (xv - g[j]) * inv2[j] * b[j] + (g[j + 3] - xv) * inv2[j + 1] * b[j + 1];
#pragma unroll
  for (int j = 0; j < 8; ++j)
    b[j] = (xv - g[j]) * inv3[j] * b[j] + (g[j + 4] - xv) * inv3[j + 1] * b[j + 1];
#pragma unroll
  for (int j = 0; j < 8; ++j) out[j] = b[j];
}

// ------------------------------------------------- A expansion (fp32 -> bf16)
__global__ __launch_bounds__(256) void expand_a(
    const float* __restrict__ x, const float* __restrict__ grid,
    __hip_bfloat16* __restrict__ A, int row0, int nrows) {
  int t = blockIdx.x * 256 + threadIdx.x;
  int n = t >> 7;                  // 128 threads per row
  if (n >= nrows) return;
  int i0 = (t & 127) * 8;

  float g[12];
  const float* gp = grid + (size_t)i0 * 12;   // rows identical by construction
#pragma unroll
  for (int j = 0; j < 12; ++j) g[j] = gp[j];
  float inv1[11], inv2[10], inv3[9];
#pragma unroll
  for (int j = 0; j < 11; ++j) inv1[j] = 1.0f / (g[j + 1] - g[j]);
#pragma unroll
  for (int j = 0; j < 10; ++j) inv2[j] = 1.0f / (g[j + 2] - g[j]);
#pragma unroll
  for (int j = 0; j < 9; ++j)  inv3[j] = 1.0f / (g[j + 3] - g[j]);

  const float* xp = x + (size_t)(row0 + n) * IN_F + i0;
  float xs[8];
  *(f32x4*)&xs[0] = *(const f32x4*)xp;
  *(f32x4*)&xs[4] = *(const f32x4*)(xp + 4);

  bf16x8 out[9];
#pragma unroll
  for (int j = 0; j < 8; ++j) {
    float xv = xs[j];
    float bas[8];
    kan_basis_fast(xv, g, inv1, inv2, inv3, bas);
    float s = xv / (1.0f + __expf(-xv));
    out[0][j] = (short)__bfloat16_as_ushort(__float2bfloat16(s));
#pragma unroll
    for (int c = 0; c < 8; ++c)
      out[c + 1][j] = (short)__bfloat16_as_ushort(__float2bfloat16(bas[c]));
  }
  __hip_bfloat16* dst = A + (size_t)n * KTOT + i0;
#pragma unroll
  for (int c = 0; c < 9; ++c)
    *(bf16x8*)(dst + (size_t)c * IN_F) = out[c];
}

// --------------------------------------------------- B packing (fp32 -> bf16)
__global__ __launch_bounds__(256) void pack_b(
    const float* __restrict__ bw, const float* __restrict__ sw,
    const float* __restrict__ sc, __hip_bfloat16* __restrict__ B) {
  int t = blockIdx.x * 256 + threadIdx.x;   // one per (o, i0/8): 1024*128
  if (t >= OUT_F * 128) return;
  int o = t >> 7;
  int i0 = (t & 127) * 8;

  float bwv[8], scv[8];
  const float* bp = bw + (size_t)o * IN_F + i0;
  const float* sp = sc + (size_t)o * IN_F + i0;
  *(f32x4*)&bwv[0] = *(const f32x4*)bp;
  *(f32x4*)&bwv[4] = *(const f32x4*)(bp + 4);
  *(f32x4*)&scv[0] = *(const f32x4*)sp;
  *(f32x4*)&scv[4] = *(const f32x4*)(sp + 4);

  bf16x8 out[9];
#pragma unroll
  for (int j = 0; j < 8; ++j) {
    out[0][j] = (short)__bfloat16_as_ushort(__float2bfloat16(bwv[j]));
    const float* swp = sw + ((size_t)o * IN_F + i0 + j) * 8;
    float swv[8];
    *(f32x4*)&swv[0] = *(const f32x4*)swp;
    *(f32x4*)&swv[4] = *(const f32x4*)(swp + 4);
#pragma unroll
    for (int c = 0; c < 8; ++c)
      out[c + 1][j] = (short)__bfloat16_as_ushort(__float2bfloat16(swv[c] * scv[j]));
  }
  __hip_bfloat16* dst = B + (size_t)o * KTOT + i0;
#pragma unroll
  for (int c = 0; c < 9; ++c)
    *(bf16x8*)(dst + (size_t)c * IN_F) = out[c];
}

// -------------------------------------------------------------- bf16 GEMM BT
// 256x128 tile, BK=64, 8 waves (64x64 each). Read-ahead single-barrier body:
// per K-tile {vmcnt(6); barrier; 16 asm ds_read (phase0's 8 first); 6 gld16
// staging t+2; lgkmcnt(8); 16 MFMA (kk=0); lgkmcnt(0); 16 MFMA (kk=1)}.
// 3-deep LDS ring staged 2 ahead. One barrier/tile is safe: each wave's
// lgkmcnt(0) precedes its next barrier arrival, so barrier-t implies all
// reads of t-1 done (slot (t+2)%3 == (t-1)%3 reusable); vmcnt(6) before the
// barrier publishes every wave's DMA of tile t. T2 swizzle both-sides.

__device__ __forceinline__ void gld16(const __hip_bfloat16* g, __hip_bfloat16* l) {
  __builtin_amdgcn_global_load_lds((AS1 void*)g, (AS3 void*)l, 16, 0, 0);
}

// inline-asm LDS read: opaque to alias analysis -> no compiler vmcnt(0) drain
__device__ __forceinline__ bf16x8 dsr128(uint32_t addr) {
  i32x4 r;
  asm volatile("ds_read_b128 %0, %1" : "=v"(r) : "v"(addr));
  return __builtin_bit_cast(bf16x8, r);
}

#define MFMA16(d, a, b) d = __builtin_amdgcn_mfma_f32_16x16x32_bf16(a, b, d, 0, 0, 0)

#define DO_TILE(VMN, STAGE) do {                                          \
    const uint32_t aS = aBase + (uint32_t)cur * (BM * BK * 2);            \
    const uint32_t bS = bBase + (uint32_t)cur * (BN * BK * 2);            \
    asm volatile("s_waitcnt vmcnt(" #VMN ")" ::: "memory");               \
    __builtin_amdgcn_sched_barrier(0);                                    \
    __builtin_amdgcn_s_barrier();                                         \
    __builtin_amdgcn_sched_barrier(0);                                    \
    bf16x8 a0 = dsr128(aS + aOffB[0][0]);                                 \
    bf16x8 a1 = dsr128(aS + aOffB[0][1]);                                 \
    bf16x8 a2 = dsr128(aS + aOffB[0][2]);                                 \
    bf16x8 a3 = dsr128(aS + aOffB[0][3]);                                 \
    bf16x8 b0 = dsr128(bS + bOffB[0][0]);                                 \
    bf16x8 b1 = dsr128(bS + bOffB[0][1]);                                 \
    bf16x8 b2 = dsr128(bS + bOffB[0][2]);                                 \
    bf16x8 b3 = dsr128(bS + bOffB[0][3]);                                 \
    bf16x8 a4 = dsr128(aS + aOffB[1][0]);                                 \
    bf16x8 a5 = dsr128(aS + aOffB[1][1]);                                 \
    bf16x8 a6 = dsr128(aS + aOffB[1][2]);                                 \
    bf16x8 a7 = dsr128(aS + aOffB[1][3]);                                 \
    bf16x8 b4 = dsr128(bS + bOffB[1][0]);                                 \
    bf16x8 b5 = dsr128(bS + bOffB[1][1]);                                 \
    bf16x8 b6 = dsr128(bS + bOffB[1][2]);                                 \
    bf16x8 b7 = dsr128(bS + bOffB[1][3]);                                 \
    STAGE                                                                 \
    __builtin_amdgcn_sched_barrier(0);                                    \
    asm volatile("s_waitcnt lgkmcnt(8)" ::: "memory");                    \
    __builtin_amdgcn_sched_barrier(0);                                    \
    __builtin_amdgcn_s_setprio(1);                                        \
    MFMA16(acc[0][0], a0, b0); MFMA16(acc[0][1], a0, b1);                 \
    MFMA16(acc[0][2], a0, b2); MFMA16(acc[0][3], a0, b3);                 \
    MFMA16(acc[1][0], a1, b0); MFMA16(acc[1][1], a1, b1);                 \
    MFMA16(acc[1][2], a1, b2); MFMA16(acc[1][3], a1, b3);                 \
    MFMA16(acc[2][0], a2, b0); MFMA16(acc[2][1], a2, b1);                 \
    MFMA16(acc[2][2], a2, b2); MFMA16(acc[2][3], a2, b3);                 \
    MFMA16(acc[3][0], a3, b0); MFMA16(acc[3][1], a3, b1);                 \
    MFMA16(acc[3][2], a3, b2); MFMA16(acc[3][3], a3, b3);                 \
    __builtin_amdgcn_s_setprio(0);                                        \
    __builtin_amdgcn_sched_barrier(0);                                    \
    asm volatile("s_waitcnt lgkmcnt(0)" ::: "memory");                    \
    __builtin_amdgcn_sched_barrier(0);                                    \
    __builtin_amdgcn_s_setprio(1);                                        \
    MFMA16(acc[0][0], a4, b4); MFMA16(acc[0][1], a4, b5);                 \
    MFMA16(acc[0][2], a4, b6); MFMA16(acc[0][3], a4, b7);                 \
    MFMA16(acc[1][0], a5, b4); MFMA16(acc[1][1], a5, b5);                 \
    MFMA16(acc[1][2], a5, b6); MFMA16(acc[1][3], a5, b7);                 \
    MFMA16(acc[2][0], a6, b4); MFMA16(acc[2][1], a6, b5);                 \
    MFMA16(acc[2][2], a6, b6); MFMA16(acc[2][3], a6, b7);                 \
    MFMA16(acc[3][0], a7, b4); MFMA16(acc[3][1], a7, b5);                 \
    MFMA16(acc[3][2], a7, b6); MFMA16(acc[3][3], a7, b7);                 \
    __builtin_amdgcn_s_setprio(0);                                        \
    __builtin_amdgcn_sched_barrier(0);                                    \
  } while (0)

__global__ __launch_bounds__(512, 2) void gemm_v5(
    const __hip_bfloat16* __restrict__ A, const __hip_bfloat16* __restrict__ B,
    float* __restrict__ C) {
  __shared__ __align__(16) __hip_bfloat16 As[3][BM * BK];  // 3 x 32 KB
  __shared__ __align__(16) __hip_bfloat16 Bs[3][BN * BK];  // 3 x 16 KB

  // T1 bijective XCD swizzle: 8 bn-blocks sharing an A-panel on one XCD
  const int nwg = gridDim.x;            // (M/256)*8, %8 == 0
  const int q = nwg >> 3;
  const int L = (blockIdx.x & 7) * q + (blockIdx.x >> 3);
  const int bm = L >> 3, bn = L & 7;

  const int tid = threadIdx.x;
  const int lane = tid & 63;
  const int wv = tid >> 6;            // 0..7
  const int wm = wv >> 1;             // 0..3 (64-row group)
  const int wn = wv & 1;              // 0..1 (64-col group)
  const int l15 = lane & 15, lhi = lane >> 4;
  const int K = KTOT;

  // ---- staging: LDS linear, global source pre-swizzled (rule #21).
  // chunk p (16B) at LDS pos p holds global chunk (row=p>>3, (p&7)^(row&7)).
  const __hip_bfloat16* aSrc[4];
  const __hip_bfloat16* bSrc[2];
  int aDst[4], bDst[2];
#pragma unroll
  for (int j = 0; j < 4; ++j) {
    int p = j * 512 + wv * 64 + lane;
    int row = p >> 3;
    int col = (p & 7) ^ (row & 7);
    aSrc[j] = A + (size_t)(bm * BM + row) * K + col * 8;
    aDst[j] = (j * 512 + wv * 64) * 8;
  }
#pragma unroll
  for (int j = 0; j < 2; ++j) {
    int p = j * 512 + wv * 64 + lane;
    int row = p >> 3;
    int col = (p & 7) ^ (row & 7);
    bSrc[j] = B + (size_t)(bn * BN + row) * K + col * 8;
    bDst[j] = (j * 512 + wv * 64) * 8;
  }

  // ---- fragment read byte-offsets (swizzled), per kk half
  const uint32_t aBase = (uint32_t)(uintptr_t)(AS3 const void*)&As[0][0];
  const uint32_t bBase = (uint32_t)(uintptr_t)(AS3 const void*)&Bs[0][0];
  uint32_t aOffB[2][4], bOffB[2][4];
#pragma unroll
  for (int kk = 0; kk < 2; ++kk)
#pragma unroll
    for (int m = 0; m < 4; ++m) {
      int rowA = wm * 64 + m * 16 + l15;
      aOffB[kk][m] = (rowA * 64 + (((kk * 4 + lhi) ^ (l15 & 7)) * 8)) * 2;
      int rowB = wn * 64 + m * 16 + l15;
      bOffB[kk][m] = (rowB * 64 + (((kk * 4 + lhi) ^ (l15 & 7)) * 8)) * 2;
    }

  f32x4 acc[4][4];
#pragma unroll
  for (int m = 0; m < 4; ++m)
#pragma unroll
    for (int n = 0; n < 4; ++n) acc[m][n] = f32x4{0.f, 0.f, 0.f, 0.f};

  // ---- prologue: stage tiles 0 and 1 (6 wave-ops each)
#pragma unroll
  for (int j = 0; j < 4; ++j) gld16(aSrc[j], &As[0][0] + aDst[j]);
#pragma unroll
  for (int j = 0; j < 2; ++j) gld16(bSrc[j], &Bs[0][0] + bDst[j]);
#pragma unroll
  for (int j = 0; j < 4; ++j) gld16(aSrc[j] + BK, &As[1][0] + aDst[j]);
#pragma unroll
  for (int j = 0; j < 2; ++j) gld16(bSrc[j] + BK, &Bs[1][0] + bDst[j]);

  int cur = 0, stg = 2;
  for (int t = 0; t < NT - 2; ++t) {
    __hip_bfloat16* asD = &As[stg][0];
    __hip_bfloat16* bsD = &Bs[stg][0];
    const int kt2 = (t + 2) * BK;
    DO_TILE(6,
      { gld16(aSrc[0] + kt2, asD + aDst[0]);
        gld16(aSrc[1] + kt2, asD + aDst[1]);
        gld16(aSrc[2] + kt2, asD + aDst[2]);
        gld16(aSrc[3] + kt2, asD + aDst[3]);
        gld16(bSrc[0] + kt2, bsD + bDst[0]);
        gld16(bSrc[1] + kt2, bsD + bDst[1]); });
    cur = cur == 2 ? 0 : cur + 1;
    stg = stg == 2 ? 0 : stg + 1;
  }
  // t = NT-2: no staging; 6 outstanding (tile NT-1)
  DO_TILE(6, {});
  cur = cur == 2 ? 0 : cur + 1;
  // t = NT-1: drain
  DO_TILE(0, {});

  // epilogue: C/D mapping col = lane&15, row = (lane>>4)*4 + reg [m89]
#pragma unroll
  for (int m = 0; m < 4; ++m)
#pragma unroll
    for (int n = 0; n < 4; ++n) {
      int col = bn * BN + wn * 64 + n * 16 + l15;
      int row0 = bm * BM + wm * 64 + m * 16 + lhi * 4;
#pragma unroll
      for (int j = 0; j < 4; ++j)
        C[(size_t)(row0 + j) * OUT_F + col] = acc[m][n][j];
    }
}

// ------------------------------------------------ naive fallback (insurance)
__global__ __launch_bounds__(256) void kan_naive(
    const float* __restrict__ x, const float* __restrict__ grid,
    const float* __restrict__ bw, const float* __restrict__ sw,
    const float* __restrict__ sc, float* __restrict__ out) {
  __shared__ float s_act[IN_F];
  __shared__ float s_bas[IN_F * 8];
  int n = blockIdx.x;
  for (int i = threadIdx.x; i < IN_F; i += 256) {
    float xv = x[(size_t)n * IN_F + i];
    float g[12];
    const float* gp = grid + i * 12;
#pragma unroll
    for (int t = 0; t < 12; ++t) g[t] = gp[t];
    float b[11];
#pragma unroll
    for (int j = 0; j < 11; ++j)
      b[j] = (xv >= g[j] && xv < g[j + 1]) ? 1.0f : 0.0f;
#pragma unroll
    for (int k = 1; k <= 3; ++k)
#pragma unroll
      for (int j = 0; j < 11 - k; ++j) {
        float left = (xv - g[j]) / (g[j + k] - g[j]);
        float right = (g[j + k + 1] - xv) / (g[j + k + 1] - g[j + 1]);
        b[j] = left * b[j] + right * b[j + 1];
      }
    s_act[i] = xv / (1.0f + __expf(-xv));
#pragma unroll
    for (int c = 0; c < 8; ++c) s_bas[i * 8 + c] = b[c];
  }
  __syncthreads();
  for (int o = threadIdx.x; o < OUT_F; o += 256) {
    float acc = 0.f;
    const float* bwo = bw + (size_t)o * IN_F;
    const float* swo = sw + (size_t)o * IN_F * 8;
    const float* sco = sc + (size_t)o * IN_F;
    for (int i = 0; i < IN_F; ++i) {
      acc += s_act[i] * bwo[i];
      float p = 0.f;
#pragma unroll
      for (int c = 0; c < 8; ++c) p += s_bas[i * 8 + c] * swo[i * 8 + c];
      acc += p * sco[i];
    }
    out[(size_t)n * OUT_F + o] = acc;
  }
}

// ---------------------------------------------------------------- launch
extern "C" void kernel_launch(void* const* d_in, const int* in_sizes, int n_in,
                              void* d_out, int out_size, void* d_ws, size_t ws_size,
                              hipStream_t stream) {
  const float* x  = (const float*)d_in[0];
  const float* grid = (const float*)d_in[1];
  const float* bw = (const float*)d_in[2];
  const float* sw = (const float*)d_in[3];
  const float* sc = (const float*)d_in[4];
  float* out = (float*)d_out;

  const size_t Bbytes = (size_t)OUT_F * KTOT * 2;   // 18.9 MB
  const size_t rowBytes = (size_t)KTOT * 2;         // 18 KB / A-row

  if (ws_size >= Bbytes + 256 * rowBytes) {
    __hip_bfloat16* Bp = (__hip_bfloat16*)d_ws;
    __hip_bfloat16* Ap = (__hip_bfloat16*)((char*)d_ws + Bbytes);
    size_t arows = (ws_size - Bbytes) / rowBytes;
    int chunk = (int)((arows / 256) * 256);
    if (chunk > M_ROWS) chunk = M_ROWS;

    pack_b<<<OUT_F * 128 / 256, 256, 0, stream>>>(bw, sw, sc, Bp);
    for (int r0 = 0; r0 < M_ROWS; r0 += chunk) {
      int rows = M_ROWS - r0 < chunk ? M_ROWS - r0 : chunk;   // multiple of 256
      expand_a<<<(rows * 128 + 255) / 256, 256, 0, stream>>>(x, grid, Ap, r0, rows);
      gemm_v5<<<(rows / BM) * 8, 512, 0, stream>>>(Ap, Bp, out + (size_t)r0 * OUT_F);
    }
  } else {
    kan_naive<<<M_ROWS, 256, 0, stream>>>(x, grid, bw, sw, sc, out);
  }
}